// Round 4
// baseline (314.228 us; speedup 1.0000x reference)
//
#include <hip/hip_runtime.h>
#include <stdint.h>

typedef unsigned short u16b;
typedef short s16x8 __attribute__((ext_vector_type(8)));
typedef unsigned short u16x4 __attribute__((ext_vector_type(4)));
typedef float f32x4 __attribute__((ext_vector_type(4)));

__device__ __forceinline__ u16b f2bf(float f) {
    uint32_t u = __float_as_uint(f);
    uint32_t r = (u + 0x7FFFu + ((u >> 16) & 1u)) >> 16;
    return (u16b)r;
}
__device__ __forceinline__ u16b f2bf_fast(float f) {
    return (u16b)((__float_as_uint(f) + 0x8000u) >> 16);
}
__device__ __forceinline__ float bf2f(u16b h) {
    return __uint_as_float(((uint32_t)h) << 16);
}

typedef const __attribute__((address_space(1))) void* gas_ptr;
typedef __attribute__((address_space(3))) void* las_ptr;
__device__ __forceinline__ void gload_lds16(const void* g, void* l) {
    __builtin_amdgcn_global_load_lds((gas_ptr)g, (las_ptr)l, 16, 0, 0);
}

// ---------------- weight cast (fp32 -> bf16) ----------------
__global__ void cast_weights(const float* __restrict__ wqkv, const float* __restrict__ wproj,
                             u16b* __restrict__ wqkv_bf, u16b* __restrict__ wproj_bf) {
    int i = blockIdx.x * 256 + threadIdx.x;
    if (i < 1536 * 512) wqkv_bf[i] = f2bf(wqkv[i]);
    if (i < 512 * 512) wproj_bf[i] = f2bf(wproj[i]);
}

// ---------------- fused 2x2 avg pool + window pack ----------------
__global__ __launch_bounds__(256) void pool_pack(const float* __restrict__ x,
                                                 u16b* __restrict__ x_hi,
                                                 u16b* __restrict__ xw) {
    int i = blockIdx.x * 256 + threadIdx.x;      // 8*1024*128 = 1M
    int c4 = i & 127;
    int t = i >> 7;                               // b*1024 + wi*32 + wj
    int wj = t & 31, wi = (t >> 5) & 31, b = t >> 10;
    const float* p00 = x + ((size_t)b * 4096 + (size_t)(wi * 2) * 64 + wj * 2) * 512 + c4 * 4;
    f32x4 v00 = *(const f32x4*)p00;
    f32x4 v01 = *(const f32x4*)(p00 + 512);
    f32x4 v10 = *(const f32x4*)(p00 + 64 * 512);
    f32x4 v11 = *(const f32x4*)(p00 + 65 * 512);

    u16b ph[4];
#pragma unroll
    for (int j = 0; j < 4; ++j)
        ph[j] = f2bf((v00[j] + v01[j] + v10[j] + v11[j]) * 0.25f);
    *(u16x4*)(x_hi + (size_t)t * 512 + c4 * 4) = *(u16x4*)ph;

    u16b pk[16];
#pragma unroll
    for (int j = 0; j < 4; ++j) {
        pk[j * 4 + 0] = f2bf(v00[j]);
        pk[j * 4 + 1] = f2bf(v01[j]);
        pk[j * 4 + 2] = f2bf(v10[j]);
        pk[j * 4 + 3] = f2bf(v11[j]);
    }
    u16b* dst = xw + ((size_t)t * 4 + (c4 >> 5)) * 512 + (c4 & 31) * 16;
    *(s16x8*)dst = *(s16x8*)pk;
    *(s16x8*)(dst + 8) = *(s16x8*)(pk + 8);
}

// ================= 256x256 8-phase GEMM, quadrant-snake operand reuse =================
// (schedule frozen since R2; see R2 comment for the stage/publish derivation)

template <int RT>  // 0=A-mLo 1=A-mHi 2=B-nLo 3=B-nHi
__device__ __forceinline__ void stage_region(const u16b* gsrc, int K, u16b* lds,
                                             int wv, int ldrow, int ldk) {
#pragma unroll
    for (int j = 0; j < 2; ++j) {
        int c = j * 8 + wv;
        int chunk;
        if (RT == 0)      chunk = c + ((c >> 3) << 3);
        else if (RT == 1) chunk = c + ((c >> 3) << 3) + 8;
        else if (RT == 2) chunk = ((c >> 2) << 3) + (c & 3);
        else              chunk = ((c >> 2) << 3) + (c & 3) + 4;
        gload_lds16(gsrc + (size_t)(chunk * 8 + ldrow) * K + ldk, lds + chunk * 512);
    }
}

template <int MH, int NH, int LA, int LB>
__device__ __forceinline__ void ds_quad(const u16b* Asb, const u16b* Bsb,
                                        int gm, int gn, int l15, int fsw0, int fsw1,
                                        s16x8 (&af)[4][2], s16x8 (&bf)[2][2]) {
    if (LA) {
#pragma unroll
        for (int i = 0; i < 4; ++i) {
            const u16b* p = Asb + (gm * 128 + (MH * 4 + i) * 16 + l15) * 64;
            af[i][0] = *(const s16x8*)(p + fsw0);
            af[i][1] = *(const s16x8*)(p + fsw1);
        }
    }
    if (LB) {
#pragma unroll
        for (int i = 0; i < 2; ++i) {
            const u16b* p = Bsb + (gn * 64 + (NH * 2 + i) * 16 + l15) * 64;
            bf[i][0] = *(const s16x8*)(p + fsw0);
            bf[i][1] = *(const s16x8*)(p + fsw1);
        }
    }
}

template <int MH, int NH>
__device__ __forceinline__ void mfma_quad(s16x8 (&af)[4][2], s16x8 (&bf)[2][2], f32x4 (&acc)[8][4]) {
    __builtin_amdgcn_s_setprio(1);
#pragma unroll
    for (int ks = 0; ks < 2; ++ks)
#pragma unroll
        for (int i = 0; i < 4; ++i)
#pragma unroll
            for (int j = 0; j < 2; ++j)
                acc[MH * 4 + i][NH * 2 + j] = __builtin_amdgcn_mfma_f32_16x16x32_bf16(
                    af[i][ks], bf[j][ks], acc[MH * 4 + i][NH * 2 + j], 0, 0, 0);
    __builtin_amdgcn_s_setprio(0);
}

template <int OUT_F32>
__global__ __launch_bounds__(512, 2) void gemm8(const u16b* __restrict__ A, const u16b* __restrict__ Bt,
                                                u16b* __restrict__ Cbf, float* __restrict__ Cf,
                                                const float* __restrict__ bias, int M, int Nn, int K,
                                                int NB) {
    __shared__ u16b As[2][256 * 64];
    __shared__ u16b Bs[2][256 * 64];
    int tid = threadIdx.x;
    int wv = tid >> 6, lane = tid & 63;
    int quad = lane >> 4, l15 = lane & 15;
    int gm = wv >> 2, gn = wv & 3;

    int nwg = gridDim.x, bid = blockIdx.x;
    int swz = (bid & 7) * (nwg >> 3) + (bid >> 3);
    int nb = swz % NB, mb = swz / NB;
    int m0 = mb * 256, n0 = nb * 256;
    const u16b* Ap = A + (size_t)m0 * K;
    const u16b* Btp = Bt + (size_t)n0 * K;

    int ldrow = lane >> 3;
    int ldk = ((lane & 7) ^ ldrow) * 8;
    int fsw0 = (quad ^ (l15 & 7)) * 8;
    int fsw1 = ((4 + quad) ^ (l15 & 7)) * 8;

    f32x4 acc[8][4] = {};
    s16x8 af[4][2], bf[2][2];
    int nt = K >> 6;

    // prologue: tile0 full -> buf0; tile1 A-mLo, B-nHi -> buf1
#pragma unroll
    for (int r = 0; r < 4; ++r) {
        int chunk = r * 8 + wv;
        gload_lds16(Ap + (size_t)(chunk * 8 + ldrow) * K + ldk, &As[0][0] + chunk * 512);
    }
#pragma unroll
    for (int r = 0; r < 4; ++r) {
        int chunk = r * 8 + wv;
        gload_lds16(Btp + (size_t)(chunk * 8 + ldrow) * K + ldk, &Bs[0][0] + chunk * 512);
    }
    stage_region<0>(Ap + 64, K, &As[1][0], wv, ldrow, ldk);
    stage_region<3>(Btp + 64, K, &Bs[1][0], wv, ldrow, ldk);
    asm volatile("s_waitcnt vmcnt(4)" ::: "memory");
    __builtin_amdgcn_s_barrier();

    for (int t0 = 0; t0 < nt; t0 += 2) {
        bool s2 = (t0 + 2) < nt;
        bool s3 = (t0 + 3) < nt;
        // ph1 (mLo,nLo) buf0 | stage A-mHi -> buf1 (t0+1)
        ds_quad<0, 0, 1, 1>(&As[0][0], &Bs[0][0], gm, gn, l15, fsw0, fsw1, af, bf);
        stage_region<1>(Ap + (size_t)(t0 + 1) * 64, K, &As[1][0], wv, ldrow, ldk);
        __builtin_amdgcn_s_barrier();
        mfma_quad<0, 0>(af, bf, acc);
        __builtin_amdgcn_s_barrier();
        // ph2 (mLo,nHi) | stage B-nLo -> buf1 (t0+1)
        ds_quad<0, 1, 0, 1>(&As[0][0], &Bs[0][0], gm, gn, l15, fsw0, fsw1, af, bf);
        stage_region<2>(Btp + (size_t)(t0 + 1) * 64, K, &Bs[1][0], wv, ldrow, ldk);
        __builtin_amdgcn_s_barrier();
        mfma_quad<0, 1>(af, bf, acc);
        __builtin_amdgcn_s_barrier();
        // ph3 (mHi,nHi) | stage A-mLo -> buf0 (t0+2)
        ds_quad<1, 1, 1, 0>(&As[0][0], &Bs[0][0], gm, gn, l15, fsw0, fsw1, af, bf);
        if (s2) stage_region<0>(Ap + (size_t)(t0 + 2) * 64, K, &As[0][0], wv, ldrow, ldk);
        __builtin_amdgcn_s_barrier();
        mfma_quad<1, 1>(af, bf, acc);
        __builtin_amdgcn_s_barrier();
        // ph4 (mHi,nLo) | stage B-nHi -> buf0 (t0+2); publish t0+1
        ds_quad<1, 0, 0, 1>(&As[0][0], &Bs[0][0], gm, gn, l15, fsw0, fsw1, af, bf);
        if (s2) stage_region<3>(Btp + (size_t)(t0 + 2) * 64, K, &Bs[0][0], wv, ldrow, ldk);
        __builtin_amdgcn_s_barrier();
        mfma_quad<1, 0>(af, bf, acc);
        if (s2) { asm volatile("s_waitcnt vmcnt(4)" ::: "memory"); }
        else    { asm volatile("s_waitcnt vmcnt(0)" ::: "memory"); }
        __builtin_amdgcn_s_barrier();
        // ph5 (mLo,nLo) buf1 | stage A-mHi -> buf0 (t0+2)
        ds_quad<0, 0, 1, 1>(&As[1][0], &Bs[1][0], gm, gn, l15, fsw0, fsw1, af, bf);
        if (s2) stage_region<1>(Ap + (size_t)(t0 + 2) * 64, K, &As[0][0], wv, ldrow, ldk);
        __builtin_amdgcn_s_barrier();
        mfma_quad<0, 0>(af, bf, acc);
        __builtin_amdgcn_s_barrier();
        // ph6 (mLo,nHi) | stage B-nLo -> buf0 (t0+2)
        ds_quad<0, 1, 0, 1>(&As[1][0], &Bs[1][0], gm, gn, l15, fsw0, fsw1, af, bf);
        if (s2) stage_region<2>(Btp + (size_t)(t0 + 2) * 64, K, &Bs[0][0], wv, ldrow, ldk);
        __builtin_amdgcn_s_barrier();
        mfma_quad<0, 1>(af, bf, acc);
        __builtin_amdgcn_s_barrier();
        // ph7 (mHi,nHi) | stage A-mLo -> buf1 (t0+3)
        ds_quad<1, 1, 1, 0>(&As[1][0], &Bs[1][0], gm, gn, l15, fsw0, fsw1, af, bf);
        if (s3) stage_region<0>(Ap + (size_t)(t0 + 3) * 64, K, &As[1][0], wv, ldrow, ldk);
        __builtin_amdgcn_s_barrier();
        mfma_quad<1, 1>(af, bf, acc);
        __builtin_amdgcn_s_barrier();
        // ph8 (mHi,nLo) | stage B-nHi -> buf1 (t0+3); publish t0+2
        ds_quad<1, 0, 0, 1>(&As[1][0], &Bs[1][0], gm, gn, l15, fsw0, fsw1, af, bf);
        if (s3) stage_region<3>(Btp + (size_t)(t0 + 3) * 64, K, &Bs[1][0], wv, ldrow, ldk);
        __builtin_amdgcn_s_barrier();
        mfma_quad<1, 0>(af, bf, acc);
        if (s3) { asm volatile("s_waitcnt vmcnt(4)" ::: "memory"); }
        else    { asm volatile("s_waitcnt vmcnt(0)" ::: "memory"); }
        __builtin_amdgcn_s_barrier();
    }

#pragma unroll
    for (int mi = 0; mi < 8; ++mi)
#pragma unroll
        for (int ni = 0; ni < 4; ++ni) {
            int row = m0 + gm * 128 + mi * 16 + quad * 4;
            int col = n0 + gn * 64 + ni * 16 + l15;
            if (OUT_F32) {
                float bv = bias[col];
#pragma unroll
                for (int r = 0; r < 4; ++r)
                    Cf[(size_t)(row + r) * Nn + col] = acc[mi][ni][r] + bv;
            } else {
#pragma unroll
                for (int r = 0; r < 4; ++r)
                    Cbf[(size_t)(row + r) * Nn + col] = f2bf(acc[mi][ni][r]);
            }
        }
}

// ---------------- V transpose for hi branch: vt[bh, d, n] ----------------
__global__ __launch_bounds__(256) void transpose_v(const u16b* __restrict__ qkv, u16b* __restrict__ vt) {
    __shared__ u16b tile[64 * 72];
    int bh = blockIdx.y, nt = blockIdx.x;
    int b = bh >> 3, h = bh & 7;
    int tid = threadIdx.x;
    int row = tid >> 2, part = tid & 3;
    const u16b* src = qkv + ((size_t)b * 1024 + nt * 64 + row) * 1536 + 1024 + h * 64 + part * 16;
    *(s16x8*)&tile[row * 72 + part * 16] = *(const s16x8*)src;
    *(s16x8*)&tile[row * 72 + part * 16 + 8] = *(const s16x8*)(src + 8);
    __syncthreads();
    u16b* dst = vt + ((size_t)bh * 64 + row) * 1024 + nt * 64 + part * 16;
#pragma unroll
    for (int j = 0; j < 16; ++j) dst[j] = tile[(part * 16 + j) * 72 + row];
}

// ---------------- hi-branch attention v5: 32 q-rows per wave ----------------
// Block = 4 waves x 32 q-rows = 128-row q-tile; grid (64 bh, 8 qb) = 512 blocks (all
// resident, 3 blocks/CU capacity at LDS=48KB). K/V fragments loaded once per wave feed
// BOTH q-halves -> LDS bytes per MFMA ~1.8x lower than v4 (the binding pipe per the
// cycle model). Same staging, swizzle, dbuf, and no-max softmax as v4.
__global__ __launch_bounds__(256, 3) void attn_hi(const u16b* __restrict__ qkv,   // [B,1024,1536]
                                                  const u16b* __restrict__ vt,    // [64,64,1024]
                                                  u16b* __restrict__ out_hi) {    // [B,1024,512]
    __shared__ u16b Ks[2][64 * 64];
    __shared__ u16b Vs[2][64 * 64];
    __shared__ u16b P[4][32 * 64];
    int tid = threadIdx.x, wave = tid >> 6, lane = tid & 63;
    int quad = lane >> 4, l15 = lane & 15;
    int bh = blockIdx.x;                   // 0..63
    int qb = blockIdx.y;                   // 0..7
    int b = bh >> 3, h = bh & 7;
    int qr0 = qb * 128 + wave * 32;

    const size_t qkv_b = (size_t)b * 1024 * 1536;
    const u16b* kg = qkv + qkv_b + 512 + h * 64;
    const u16b* vg = vt + (size_t)bh * 64 * 1024;

    int srow8 = lane >> 3;
    int ssw = ((lane & 7) ^ srow8) * 8;
    int fsw0 = (quad ^ (l15 & 7)) * 8;
    int fsw1 = ((4 + quad) ^ (l15 & 7)) * 8;

    s16x8 qf[2][2];
#pragma unroll
    for (int qh = 0; qh < 2; ++qh) {
        const u16b* qp = qkv + qkv_b + (size_t)(qr0 + qh * 16 + l15) * 1536 + h * 64 + quad * 8;
        qf[qh][0] = *(const s16x8*)qp;
        qf[qh][1] = *(const s16x8*)(qp + 32);
    }

    // prologue: stage tile 0 into buffer 0 (each wave covers chunks wave*2, wave*2+1)
#pragma unroll
    for (int i = 0; i < 2; ++i) {
        int chunk = wave * 2 + i;
        int row = chunk * 8 + srow8;
        gload_lds16(kg + (size_t)row * 1536 + ssw, (u16b*)Ks[0] + chunk * 512);
        gload_lds16(vg + (size_t)row * 1024 + ssw, (u16b*)Vs[0] + chunk * 512);
    }

    f32x4 o[2][4] = {};
    f32x4 ls[2] = {};
    u16b* pl = P[wave];
    const float c_scale = 0.18033688011f;   // 0.125 * log2(e)

    for (int kb = 0; kb < 16; ++kb) {
        int cur = kb & 1, nxt = cur ^ 1;
        __syncthreads();   // tile kb staged; all waves done with buffer nxt
        if (kb < 15) {
#pragma unroll
            for (int i = 0; i < 2; ++i) {
                int chunk = wave * 2 + i;
                int row = chunk * 8 + srow8;
                gload_lds16(kg + (size_t)((kb + 1) * 64 + row) * 1536 + ssw, (u16b*)Ks[nxt] + chunk * 512);
                gload_lds16(vg + (size_t)row * 1024 + (kb + 1) * 64 + ssw, (u16b*)Vs[nxt] + chunk * 512);
            }
        }
        const u16b* Kc = Ks[cur];
        const u16b* Vc = Vs[cur];

        f32x4 s[2][4] = {};
#pragma unroll
        for (int nt = 0; nt < 4; ++nt) {
            s16x8 kf0 = *(const s16x8*)(Kc + (nt * 16 + l15) * 64 + fsw0);
            s16x8 kf1 = *(const s16x8*)(Kc + (nt * 16 + l15) * 64 + fsw1);
            s[0][nt] = __builtin_amdgcn_mfma_f32_16x16x32_bf16(qf[0][0], kf0, s[0][nt], 0, 0, 0);
            s[0][nt] = __builtin_amdgcn_mfma_f32_16x16x32_bf16(qf[0][1], kf1, s[0][nt], 0, 0, 0);
            s[1][nt] = __builtin_amdgcn_mfma_f32_16x16x32_bf16(qf[1][0], kf0, s[1][nt], 0, 0, 0);
            s[1][nt] = __builtin_amdgcn_mfma_f32_16x16x32_bf16(qf[1][1], kf1, s[1][nt], 0, 0, 0);
        }
#pragma unroll
        for (int qh = 0; qh < 2; ++qh)
#pragma unroll
            for (int nt = 0; nt < 4; ++nt) {
                f32x4 p;
#pragma unroll
                for (int r = 0; r < 4; ++r) p[r] = exp2f(s[qh][nt][r] * c_scale);
                ls[qh] += p;
#pragma unroll
                for (int r = 0; r < 4; ++r) {
                    int prow = qh * 16 + quad * 4 + r;
                    int slc = (nt * 2 + (l15 >> 3)) ^ (prow & 7);
                    pl[prow * 64 + slc * 8 + (l15 & 7)] = f2bf_fast(p[r]);
                }
            }
        s16x8 pa[2][2];
#pragma unroll
        for (int qh = 0; qh < 2; ++qh) {
            pa[qh][0] = *(const s16x8*)(pl + (qh * 16 + l15) * 64 + fsw0);
            pa[qh][1] = *(const s16x8*)(pl + (qh * 16 + l15) * 64 + fsw1);
        }
#pragma unroll
        for (int nd = 0; nd < 4; ++nd) {
            s16x8 vf0 = *(const s16x8*)(Vc + (nd * 16 + l15) * 64 + fsw0);
            s16x8 vf1 = *(const s16x8*)(Vc + (nd * 16 + l15) * 64 + fsw1);
            o[0][nd] = __builtin_amdgcn_mfma_f32_16x16x32_bf16(pa[0][0], vf0, o[0][nd], 0, 0, 0);
            o[0][nd] = __builtin_amdgcn_mfma_f32_16x16x32_bf16(pa[0][1], vf1, o[0][nd], 0, 0, 0);
            o[1][nd] = __builtin_amdgcn_mfma_f32_16x16x32_bf16(pa[1][0], vf0, o[1][nd], 0, 0, 0);
            o[1][nd] = __builtin_amdgcn_mfma_f32_16x16x32_bf16(pa[1][1], vf1, o[1][nd], 0, 0, 0);
        }
    }

#pragma unroll
    for (int qh = 0; qh < 2; ++qh) {
        float rs[4];
#pragma unroll
        for (int r = 0; r < 4; ++r) {
            float t = ls[qh][r];
#pragma unroll
            for (int msk = 1; msk < 16; msk <<= 1) t += __shfl_xor(t, msk);
            rs[r] = 1.f / t;
        }
#pragma unroll
        for (int nd = 0; nd < 4; ++nd)
#pragma unroll
            for (int r = 0; r < 4; ++r) {
                int row = qr0 + qh * 16 + quad * 4 + r;
                int col = h * 64 + nd * 16 + l15;
                out_hi[((size_t)b * 1024 + row) * 512 + col] = f2bf(o[qh][nd][r] * rs[r]);
            }
    }
}

// ---------------- lo-branch windowed attention: MFMA QK^T + LDS-P + VALU PV ----------------
__global__ __launch_bounds__(256) void attn_lo_up(const u16b* __restrict__ qkv_lo,  // [B,1024,4,1536]
                                                  const u16b* __restrict__ out_hi,  // [B,1024,512]
                                                  u16b* __restrict__ attn_sum) {    // [B,4096,512]
    __shared__ float P[4][64];               // [wave][win*16 + tq*4 + tk]
    int tid = threadIdx.x, wave = tid >> 6, lane = tid & 63;
    int quad = lane >> 4, l15 = lane & 15;
    int wg = blockIdx.x * 4 + wave;          // 0..16383
    int h = wg & 7, w4 = (wg >> 3) & 255, b = wg >> 11;
    int w0 = w4 * 4;

    const u16b* qb = qkv_lo + ((size_t)(b * 1024 + w0 + (l15 >> 2)) * 4 + (l15 & 3)) * 1536 + h * 64 + quad * 8;
    s16x8 qf0 = *(const s16x8*)qb;
    s16x8 qf1 = *(const s16x8*)(qb + 32);
    s16x8 kf0 = *(const s16x8*)(qb + 512);
    s16x8 kf1 = *(const s16x8*)(qb + 544);
    f32x4 s = {};
    s = __builtin_amdgcn_mfma_f32_16x16x32_bf16(qf0, kf0, s, 0, 0, 0);
    s = __builtin_amdgcn_mfma_f32_16x16x32_bf16(qf1, kf1, s, 0, 0, 0);
    bool valid = (l15 >> 2) == quad;
    float* pl = &P[wave][quad * 16];
#pragma unroll
    for (int r = 0; r < 4; ++r) {
        float v = s[r] * 0.125f;
        float m = fmaxf(v, __shfl_xor(v, 1));
        m = fmaxf(m, __shfl_xor(m, 2));
        float e = exp2f((v - m) * 1.44269504f);
        float sm = e + __shfl_xor(e, 1);
        sm += __shfl_xor(sm, 2);
        if (valid) pl[r * 4 + (l15 & 3)] = e / sm;
    }

    int win = quad, d4 = l15 * 4;
    int w = w0 + win;
    int wi = w >> 5, wj = w & 31;
    const u16b* vb = qkv_lo + ((size_t)(b * 1024 + w) * 4) * 1536 + 1024 + h * 64 + d4;
    float vf[4][4];
#pragma unroll
    for (int tk = 0; tk < 4; ++tk) {
        u16x4 vv = *(const u16x4*)(vb + (size_t)tk * 1536);
#pragma unroll
        for (int j = 0; j < 4; ++j) vf[tk][j] = bf2f(vv[j]);
    }
    int rr[3] = { wi > 0 ? wi - 1 : 0, wi, wi < 31 ? wi + 1 : 31 };
    int cc[3] = { wj > 0 ? wj - 1 : 0, wj, wj < 31 ? wj + 1 : 31 };
    float hv[3][3][4];
    const u16b* hb = out_hi + (size_t)b * 1024 * 512 + h * 64 + d4;
#pragma unroll
    for (int iy = 0; iy < 3; ++iy)
#pragma unroll
        for (int ix = 0; ix < 3; ++ix) {
            u16x4 t = *(const u16x4*)(hb + (size_t)(rr[iy] * 32 + cc[ix]) * 512);
#pragma unroll
            for (int j = 0; j < 4; ++j) hv[iy][ix][j] = bf2f(t[j]);
        }
#pragma unroll
    for (int tq = 0; tq < 4; ++tq) {
        f32x4 pq = *(const f32x4*)&P[wave][win * 16 + tq * 4];
        int py = tq >> 1, px = tq & 1;
        float wy0 = py ? 0.75f : 0.25f, wx0 = px ? 0.75f : 0.25f;
        float wy1 = 1.f - wy0, wx1 = 1.f - wx0;
        u16b ov[4];
#pragma unroll
        for (int j = 0; j < 4; ++j) {
            float o = pq[0] * vf[0][j] + pq[1] * vf[1][j] + pq[2] * vf[2][j] + pq[3] * vf[3][j];
            float vu = wy0 * (wx0 * hv[py][px][j] + wx1 * hv[py][px + 1][j])
                     + wy1 * (wx0 * hv[py + 1][px][j] + wx1 * hv[py + 1][px + 1][j]);
            ov[j] = f2bf(o + vu);
        }
        int n = (wi * 2 + py) * 64 + wj * 2 + px;
        *(u16x4*)(attn_sum + ((size_t)(b * 4096 + n)) * 512 + h * 64 + d4) = *(u16x4*)ov;
    }
}

// ---------------- launch ----------------
extern "C" void kernel_launch(void* const* d_in, const int* in_sizes, int n_in,
                              void* d_out, int out_size, void* d_ws, size_t ws_size,
                              hipStream_t stream) {
    (void)in_sizes; (void)n_in; (void)out_size; (void)ws_size;
    const float* x = (const float*)d_in[0];
    const float* Wqkv = (const float*)d_in[1];
    const float* Wproj = (const float*)d_in[2];
    const float* bproj = (const float*)d_in[3];
    float* out = (float*)d_out;

    char* ws = (char*)d_ws;
    size_t off = 0;
    auto alloc = [&](size_t bytes) { void* p = ws + off; off += bytes; return p; };
    u16b* wqkv_bf = (u16b*)alloc((size_t)1536 * 512 * 2);
    u16b* wproj_bf = (u16b*)alloc((size_t)512 * 512 * 2);
    // xw and x_hi contiguous -> single merged A of 40960 rows; same for qkv_lo|qkv_hi
    u16b* xw      = (u16b*)alloc((size_t)8 * 1024 * 4 * 512 * 2);
    u16b* x_hi    = (u16b*)alloc((size_t)8 * 1024 * 512 * 2);
    u16b* qkv_lo  = (u16b*)alloc((size_t)8 * 4096 * 1536 * 2);
    u16b* qkv_hi  = (u16b*)alloc((size_t)8 * 1024 * 1536 * 2);
    u16b* vt      = (u16b*)alloc((size_t)64 * 64 * 1024 * 2);
    u16b* out_hi  = (u16b*)alloc((size_t)8 * 1024 * 512 * 2);
    u16b* attn_sum= (u16b*)alloc((size_t)8 * 4096 * 512 * 2);

    cast_weights<<<dim3(3072), dim3(256), 0, stream>>>(Wqkv, Wproj, wqkv_bf, wproj_bf);
    pool_pack<<<dim3(4096), dim3(256), 0, stream>>>(x, x_hi, xw);
    // merged qkv GEMM: M = 32768 (windows) + 8192 (pooled) = 40960 rows
    gemm8<0><<<dim3(960), dim3(512), 0, stream>>>(xw, wqkv_bf, qkv_lo, nullptr, nullptr, 40960, 1536, 512, 6);
    transpose_v<<<dim3(16, 64), dim3(256), 0, stream>>>(qkv_hi, vt);
    attn_hi<<<dim3(64, 8), dim3(256), 0, stream>>>(qkv_hi, vt, out_hi);
    attn_lo_up<<<dim3(4096), dim3(256), 0, stream>>>(qkv_lo, out_hi, attn_sum);
    gemm8<1><<<dim3(256), dim3(512), 0, stream>>>(attn_sum, wproj_bf, nullptr, out, bproj, 32768, 512, 512, 2);
}

// Round 5
// 301.142 us; speedup vs baseline: 1.0435x; 1.0435x over previous
//
#include <hip/hip_runtime.h>
#include <stdint.h>

typedef unsigned short u16b;
typedef short s16x8 __attribute__((ext_vector_type(8)));
typedef unsigned short u16x4 __attribute__((ext_vector_type(4)));
typedef float f32x4 __attribute__((ext_vector_type(4)));

__device__ __forceinline__ u16b f2bf(float f) {
    uint32_t u = __float_as_uint(f);
    uint32_t r = (u + 0x7FFFu + ((u >> 16) & 1u)) >> 16;
    return (u16b)r;
}
__device__ __forceinline__ u16b f2bf_fast(float f) {
    return (u16b)((__float_as_uint(f) + 0x8000u) >> 16);
}
__device__ __forceinline__ float bf2f(u16b h) {
    return __uint_as_float(((uint32_t)h) << 16);
}

typedef const __attribute__((address_space(1))) void* gas_ptr;
typedef __attribute__((address_space(3))) void* las_ptr;
__device__ __forceinline__ void gload_lds16(const void* g, void* l) {
    __builtin_amdgcn_global_load_lds((gas_ptr)g, (las_ptr)l, 16, 0, 0);
}

// ---------------- fused weight-cast + 2x2 avg pool + window pack (one launch) ----------------
__global__ __launch_bounds__(256) void pool_pack_cast(const float* __restrict__ x,
                                                      u16b* __restrict__ x_hi,
                                                      u16b* __restrict__ xw,
                                                      const float* __restrict__ wqkv,
                                                      const float* __restrict__ wproj,
                                                      u16b* __restrict__ wqkv_bf,
                                                      u16b* __restrict__ wproj_bf) {
    int bid = blockIdx.x;
    if (bid >= 4096) {
        int i = (bid - 4096) * 256 + threadIdx.x;
        if (i < 1536 * 512) wqkv_bf[i] = f2bf(wqkv[i]);
        if (i < 512 * 512) wproj_bf[i] = f2bf(wproj[i]);
        return;
    }
    int i = bid * 256 + threadIdx.x;             // 8*1024*128 = 1M
    int c4 = i & 127;
    int t = i >> 7;                               // b*1024 + wi*32 + wj
    int wj = t & 31, wi = (t >> 5) & 31, b = t >> 10;
    const float* p00 = x + ((size_t)b * 4096 + (size_t)(wi * 2) * 64 + wj * 2) * 512 + c4 * 4;
    f32x4 v00 = *(const f32x4*)p00;
    f32x4 v01 = *(const f32x4*)(p00 + 512);
    f32x4 v10 = *(const f32x4*)(p00 + 64 * 512);
    f32x4 v11 = *(const f32x4*)(p00 + 65 * 512);

    u16b ph[4];
#pragma unroll
    for (int j = 0; j < 4; ++j)
        ph[j] = f2bf((v00[j] + v01[j] + v10[j] + v11[j]) * 0.25f);
    *(u16x4*)(x_hi + (size_t)t * 512 + c4 * 4) = *(u16x4*)ph;

    u16b pk[16];
#pragma unroll
    for (int j = 0; j < 4; ++j) {
        pk[j * 4 + 0] = f2bf(v00[j]);
        pk[j * 4 + 1] = f2bf(v01[j]);
        pk[j * 4 + 2] = f2bf(v10[j]);
        pk[j * 4 + 3] = f2bf(v11[j]);
    }
    u16b* dst = xw + ((size_t)t * 4 + (c4 >> 5)) * 512 + (c4 & 31) * 16;
    *(s16x8*)dst = *(s16x8*)pk;
    *(s16x8*)(dst + 8) = *(s16x8*)(pk + 8);
}

// ================= 256x256 8-phase GEMM, quadrant-snake operand reuse =================
// (schedule frozen since R2; see R2 comment for the stage/publish derivation)

template <int RT>  // 0=A-mLo 1=A-mHi 2=B-nLo 3=B-nHi
__device__ __forceinline__ void stage_region(const u16b* gsrc, int K, u16b* lds,
                                             int wv, int ldrow, int ldk) {
#pragma unroll
    for (int j = 0; j < 2; ++j) {
        int c = j * 8 + wv;
        int chunk;
        if (RT == 0)      chunk = c + ((c >> 3) << 3);
        else if (RT == 1) chunk = c + ((c >> 3) << 3) + 8;
        else if (RT == 2) chunk = ((c >> 2) << 3) + (c & 3);
        else              chunk = ((c >> 2) << 3) + (c & 3) + 4;
        gload_lds16(gsrc + (size_t)(chunk * 8 + ldrow) * K + ldk, lds + chunk * 512);
    }
}

template <int MH, int NH, int LA, int LB>
__device__ __forceinline__ void ds_quad(const u16b* Asb, const u16b* Bsb,
                                        int gm, int gn, int l15, int fsw0, int fsw1,
                                        s16x8 (&af)[4][2], s16x8 (&bf)[2][2]) {
    if (LA) {
#pragma unroll
        for (int i = 0; i < 4; ++i) {
            const u16b* p = Asb + (gm * 128 + (MH * 4 + i) * 16 + l15) * 64;
            af[i][0] = *(const s16x8*)(p + fsw0);
            af[i][1] = *(const s16x8*)(p + fsw1);
        }
    }
    if (LB) {
#pragma unroll
        for (int i = 0; i < 2; ++i) {
            const u16b* p = Bsb + (gn * 64 + (NH * 2 + i) * 16 + l15) * 64;
            bf[i][0] = *(const s16x8*)(p + fsw0);
            bf[i][1] = *(const s16x8*)(p + fsw1);
        }
    }
}

template <int MH, int NH>
__device__ __forceinline__ void mfma_quad(s16x8 (&af)[4][2], s16x8 (&bf)[2][2], f32x4 (&acc)[8][4]) {
    __builtin_amdgcn_s_setprio(1);
#pragma unroll
    for (int ks = 0; ks < 2; ++ks)
#pragma unroll
        for (int i = 0; i < 4; ++i)
#pragma unroll
            for (int j = 0; j < 2; ++j)
                acc[MH * 4 + i][NH * 2 + j] = __builtin_amdgcn_mfma_f32_16x16x32_bf16(
                    af[i][ks], bf[j][ks], acc[MH * 4 + i][NH * 2 + j], 0, 0, 0);
    __builtin_amdgcn_s_setprio(0);
}

template <int OUT_F32>
__global__ __launch_bounds__(512, 2) void gemm8(const u16b* __restrict__ A, const u16b* __restrict__ Bt,
                                                u16b* __restrict__ Cbf, float* __restrict__ Cf,
                                                const float* __restrict__ bias, int M, int Nn, int K,
                                                int NB) {
    __shared__ u16b As[2][256 * 64];
    __shared__ u16b Bs[2][256 * 64];
    int tid = threadIdx.x;
    int wv = tid >> 6, lane = tid & 63;
    int quad = lane >> 4, l15 = lane & 15;
    int gm = wv >> 2, gn = wv & 3;

    int nwg = gridDim.x, bid = blockIdx.x;
    int swz = (bid & 7) * (nwg >> 3) + (bid >> 3);
    int nb = swz % NB, mb = swz / NB;
    int m0 = mb * 256, n0 = nb * 256;
    const u16b* Ap = A + (size_t)m0 * K;
    const u16b* Btp = Bt + (size_t)n0 * K;

    int ldrow = lane >> 3;
    int ldk = ((lane & 7) ^ ldrow) * 8;
    int fsw0 = (quad ^ (l15 & 7)) * 8;
    int fsw1 = ((4 + quad) ^ (l15 & 7)) * 8;

    f32x4 acc[8][4] = {};
    s16x8 af[4][2], bf[2][2];
    int nt = K >> 6;

    // prologue: tile0 full -> buf0; tile1 A-mLo, B-nHi -> buf1
#pragma unroll
    for (int r = 0; r < 4; ++r) {
        int chunk = r * 8 + wv;
        gload_lds16(Ap + (size_t)(chunk * 8 + ldrow) * K + ldk, &As[0][0] + chunk * 512);
    }
#pragma unroll
    for (int r = 0; r < 4; ++r) {
        int chunk = r * 8 + wv;
        gload_lds16(Btp + (size_t)(chunk * 8 + ldrow) * K + ldk, &Bs[0][0] + chunk * 512);
    }
    stage_region<0>(Ap + 64, K, &As[1][0], wv, ldrow, ldk);
    stage_region<3>(Btp + 64, K, &Bs[1][0], wv, ldrow, ldk);
    asm volatile("s_waitcnt vmcnt(4)" ::: "memory");
    __builtin_amdgcn_s_barrier();

    for (int t0 = 0; t0 < nt; t0 += 2) {
        bool s2 = (t0 + 2) < nt;
        bool s3 = (t0 + 3) < nt;
        // ph1 (mLo,nLo) buf0 | stage A-mHi -> buf1 (t0+1)
        ds_quad<0, 0, 1, 1>(&As[0][0], &Bs[0][0], gm, gn, l15, fsw0, fsw1, af, bf);
        stage_region<1>(Ap + (size_t)(t0 + 1) * 64, K, &As[1][0], wv, ldrow, ldk);
        __builtin_amdgcn_s_barrier();
        mfma_quad<0, 0>(af, bf, acc);
        __builtin_amdgcn_s_barrier();
        // ph2 (mLo,nHi) | stage B-nLo -> buf1 (t0+1)
        ds_quad<0, 1, 0, 1>(&As[0][0], &Bs[0][0], gm, gn, l15, fsw0, fsw1, af, bf);
        stage_region<2>(Btp + (size_t)(t0 + 1) * 64, K, &Bs[1][0], wv, ldrow, ldk);
        __builtin_amdgcn_s_barrier();
        mfma_quad<0, 1>(af, bf, acc);
        __builtin_amdgcn_s_barrier();
        // ph3 (mHi,nHi) | stage A-mLo -> buf0 (t0+2)
        ds_quad<1, 1, 1, 0>(&As[0][0], &Bs[0][0], gm, gn, l15, fsw0, fsw1, af, bf);
        if (s2) stage_region<0>(Ap + (size_t)(t0 + 2) * 64, K, &As[0][0], wv, ldrow, ldk);
        __builtin_amdgcn_s_barrier();
        mfma_quad<1, 1>(af, bf, acc);
        __builtin_amdgcn_s_barrier();
        // ph4 (mHi,nLo) | stage B-nHi -> buf0 (t0+2); publish t0+1
        ds_quad<1, 0, 0, 1>(&As[0][0], &Bs[0][0], gm, gn, l15, fsw0, fsw1, af, bf);
        if (s2) stage_region<3>(Btp + (size_t)(t0 + 2) * 64, K, &Bs[0][0], wv, ldrow, ldk);
        __builtin_amdgcn_s_barrier();
        mfma_quad<1, 0>(af, bf, acc);
        if (s2) { asm volatile("s_waitcnt vmcnt(4)" ::: "memory"); }
        else    { asm volatile("s_waitcnt vmcnt(0)" ::: "memory"); }
        __builtin_amdgcn_s_barrier();
        // ph5 (mLo,nLo) buf1 | stage A-mHi -> buf0 (t0+2)
        ds_quad<0, 0, 1, 1>(&As[1][0], &Bs[1][0], gm, gn, l15, fsw0, fsw1, af, bf);
        if (s2) stage_region<1>(Ap + (size_t)(t0 + 2) * 64, K, &As[0][0], wv, ldrow, ldk);
        __builtin_amdgcn_s_barrier();
        mfma_quad<0, 0>(af, bf, acc);
        __builtin_amdgcn_s_barrier();
        // ph6 (mLo,nHi) | stage B-nLo -> buf0 (t0+2)
        ds_quad<0, 1, 0, 1>(&As[1][0], &Bs[1][0], gm, gn, l15, fsw0, fsw1, af, bf);
        if (s2) stage_region<2>(Btp + (size_t)(t0 + 2) * 64, K, &Bs[0][0], wv, ldrow, ldk);
        __builtin_amdgcn_s_barrier();
        mfma_quad<0, 1>(af, bf, acc);
        __builtin_amdgcn_s_barrier();
        // ph7 (mHi,nHi) | stage A-mLo -> buf1 (t0+3)
        ds_quad<1, 1, 1, 0>(&As[1][0], &Bs[1][0], gm, gn, l15, fsw0, fsw1, af, bf);
        if (s3) stage_region<0>(Ap + (size_t)(t0 + 3) * 64, K, &As[1][0], wv, ldrow, ldk);
        __builtin_amdgcn_s_barrier();
        mfma_quad<1, 1>(af, bf, acc);
        __builtin_amdgcn_s_barrier();
        // ph8 (mHi,nLo) | stage B-nHi -> buf1 (t0+3); publish t0+2
        ds_quad<1, 0, 0, 1>(&As[1][0], &Bs[1][0], gm, gn, l15, fsw0, fsw1, af, bf);
        if (s3) stage_region<3>(Btp + (size_t)(t0 + 3) * 64, K, &Bs[1][0], wv, ldrow, ldk);
        __builtin_amdgcn_s_barrier();
        mfma_quad<1, 0>(af, bf, acc);
        if (s3) { asm volatile("s_waitcnt vmcnt(4)" ::: "memory"); }
        else    { asm volatile("s_waitcnt vmcnt(0)" ::: "memory"); }
        __builtin_amdgcn_s_barrier();
    }

#pragma unroll
    for (int mi = 0; mi < 8; ++mi)
#pragma unroll
        for (int ni = 0; ni < 4; ++ni) {
            int row = m0 + gm * 128 + mi * 16 + quad * 4;
            int col = n0 + gn * 64 + ni * 16 + l15;
            if (OUT_F32) {
                float bv = bias[col];
#pragma unroll
                for (int r = 0; r < 4; ++r)
                    Cf[(size_t)(row + r) * Nn + col] = acc[mi][ni][r] + bv;
            } else {
#pragma unroll
                for (int r = 0; r < 4; ++r)
                    Cbf[(size_t)(row + r) * Nn + col] = f2bf(acc[mi][ni][r]);
            }
        }
}

// ---------------- V transpose for hi branch: vt[bh, d, n] ----------------
__global__ __launch_bounds__(256) void transpose_v(const u16b* __restrict__ qkv, u16b* __restrict__ vt) {
    __shared__ u16b tile[64 * 72];
    int bh = blockIdx.y, nt = blockIdx.x;
    int b = bh >> 3, h = bh & 7;
    int tid = threadIdx.x;
    int row = tid >> 2, part = tid & 3;
    const u16b* src = qkv + ((size_t)b * 1024 + nt * 64 + row) * 1536 + 1024 + h * 64 + part * 16;
    *(s16x8*)&tile[row * 72 + part * 16] = *(const s16x8*)src;
    *(s16x8*)&tile[row * 72 + part * 16 + 8] = *(const s16x8*)(src + 8);
    __syncthreads();
    u16b* dst = vt + ((size_t)bh * 64 + row) * 1024 + nt * 64 + part * 16;
#pragma unroll
    for (int j = 0; j < 16; ++j) dst[j] = tile[(part * 16 + j) * 72 + row];
}

// ---------------- hi-branch attention v4 (reverted: 16 q-rows/wave, 4 blocks/CU) ----------------
// v5 (32 rows/wave, 2 blocks/CU) regressed ~15us: halved resident blocks exposed the
// per-K-tile HBM prefetch latency that independent blocks otherwise cover.
__global__ __launch_bounds__(256) void attn_hi(const u16b* __restrict__ qkv,   // [B,1024,1536]
                                               const u16b* __restrict__ vt,    // [64,64,1024]
                                               u16b* __restrict__ out_hi) {    // [B,1024,512]
    __shared__ u16b Ks[2][64 * 64];
    __shared__ u16b Vs[2][64 * 64];
    __shared__ u16b P[4][16 * 64];
    int tid = threadIdx.x, wave = tid >> 6, lane = tid & 63;
    int quad = lane >> 4, l15 = lane & 15;
    int bh = blockIdx.x;
    int qb = blockIdx.y;
    int b = bh >> 3, h = bh & 7;
    int qr0 = qb * 64 + wave * 16;

    const size_t qkv_b = (size_t)b * 1024 * 1536;
    const u16b* kg = qkv + qkv_b + 512 + h * 64;
    const u16b* vg = vt + (size_t)bh * 64 * 1024;

    int srow8 = lane >> 3;
    int ssw = ((lane & 7) ^ srow8) * 8;
    int fsw0 = (quad ^ (l15 & 7)) * 8;
    int fsw1 = ((4 + quad) ^ (l15 & 7)) * 8;

    s16x8 qf[2];
    qf[0] = *(const s16x8*)(qkv + qkv_b + (size_t)(qr0 + l15) * 1536 + h * 64 + quad * 8);
    qf[1] = *(const s16x8*)(qkv + qkv_b + (size_t)(qr0 + l15) * 1536 + h * 64 + 32 + quad * 8);

#pragma unroll
    for (int i = 0; i < 2; ++i) {
        int chunk = wave * 2 + i;
        int row = chunk * 8 + srow8;
        gload_lds16(kg + (size_t)row * 1536 + ssw, (u16b*)Ks[0] + chunk * 512);
        gload_lds16(vg + (size_t)row * 1024 + ssw, (u16b*)Vs[0] + chunk * 512);
    }

    f32x4 o[4] = {};
    f32x4 ls = {0.f, 0.f, 0.f, 0.f};
    u16b* pl = P[wave];
    const float c_scale = 0.18033688011f;   // 0.125 * log2(e)

    for (int kb = 0; kb < 16; ++kb) {
        int cur = kb & 1, nxt = cur ^ 1;
        __syncthreads();
        if (kb < 15) {
#pragma unroll
            for (int i = 0; i < 2; ++i) {
                int chunk = wave * 2 + i;
                int row = chunk * 8 + srow8;
                gload_lds16(kg + (size_t)((kb + 1) * 64 + row) * 1536 + ssw, (u16b*)Ks[nxt] + chunk * 512);
                gload_lds16(vg + (size_t)row * 1024 + (kb + 1) * 64 + ssw, (u16b*)Vs[nxt] + chunk * 512);
            }
        }
        const u16b* Kc = Ks[cur];
        const u16b* Vc = Vs[cur];

        f32x4 s[4] = {};
#pragma unroll
        for (int nt = 0; nt < 4; ++nt) {
            s16x8 kf0 = *(const s16x8*)(Kc + (nt * 16 + l15) * 64 + fsw0);
            s16x8 kf1 = *(const s16x8*)(Kc + (nt * 16 + l15) * 64 + fsw1);
            s[nt] = __builtin_amdgcn_mfma_f32_16x16x32_bf16(qf[0], kf0, s[nt], 0, 0, 0);
            s[nt] = __builtin_amdgcn_mfma_f32_16x16x32_bf16(qf[1], kf1, s[nt], 0, 0, 0);
        }
#pragma unroll
        for (int nt = 0; nt < 4; ++nt) {
            f32x4 p;
#pragma unroll
            for (int r = 0; r < 4; ++r) p[r] = exp2f(s[nt][r] * c_scale);
            ls += p;
#pragma unroll
            for (int r = 0; r < 4; ++r) {
                int prow = quad * 4 + r;
                int slc = (nt * 2 + (l15 >> 3)) ^ (prow & 7);
                pl[prow * 64 + slc * 8 + (l15 & 7)] = f2bf_fast(p[r]);
            }
        }
        s16x8 pa0 = *(const s16x8*)(pl + l15 * 64 + fsw0);
        s16x8 pa1 = *(const s16x8*)(pl + l15 * 64 + fsw1);
#pragma unroll
        for (int nd = 0; nd < 4; ++nd) {
            s16x8 vf0 = *(const s16x8*)(Vc + (nd * 16 + l15) * 64 + fsw0);
            s16x8 vf1 = *(const s16x8*)(Vc + (nd * 16 + l15) * 64 + fsw1);
            o[nd] = __builtin_amdgcn_mfma_f32_16x16x32_bf16(pa0, vf0, o[nd], 0, 0, 0);
            o[nd] = __builtin_amdgcn_mfma_f32_16x16x32_bf16(pa1, vf1, o[nd], 0, 0, 0);
        }
    }

    float rs[4];
#pragma unroll
    for (int r = 0; r < 4; ++r) {
        float t = ls[r];
#pragma unroll
        for (int msk = 1; msk < 16; msk <<= 1) t += __shfl_xor(t, msk);
        rs[r] = 1.f / t;
    }
#pragma unroll
    for (int nd = 0; nd < 4; ++nd)
#pragma unroll
        for (int r = 0; r < 4; ++r) {
            int row = qr0 + quad * 4 + r;
            int col = h * 64 + nd * 16 + l15;
            out_hi[((size_t)b * 1024 + row) * 512 + col] = f2bf(o[nd][r] * rs[r]);
        }
}

// ---------------- lo-branch windowed attention: MFMA QK^T + LDS-P + VALU PV ----------------
__global__ __launch_bounds__(256) void attn_lo_up(const u16b* __restrict__ qkv_lo,  // [B,1024,4,1536]
                                                  const u16b* __restrict__ out_hi,  // [B,1024,512]
                                                  u16b* __restrict__ attn_sum) {    // [B,4096,512]
    __shared__ float P[4][64];               // [wave][win*16 + tq*4 + tk]
    int tid = threadIdx.x, wave = tid >> 6, lane = tid & 63;
    int quad = lane >> 4, l15 = lane & 15;
    int wg = blockIdx.x * 4 + wave;          // 0..16383
    int h = wg & 7, w4 = (wg >> 3) & 255, b = wg >> 11;
    int w0 = w4 * 4;

    const u16b* qb = qkv_lo + ((size_t)(b * 1024 + w0 + (l15 >> 2)) * 4 + (l15 & 3)) * 1536 + h * 64 + quad * 8;
    s16x8 qf0 = *(const s16x8*)qb;
    s16x8 qf1 = *(const s16x8*)(qb + 32);
    s16x8 kf0 = *(const s16x8*)(qb + 512);
    s16x8 kf1 = *(const s16x8*)(qb + 544);
    f32x4 s = {};
    s = __builtin_amdgcn_mfma_f32_16x16x32_bf16(qf0, kf0, s, 0, 0, 0);
    s = __builtin_amdgcn_mfma_f32_16x16x32_bf16(qf1, kf1, s, 0, 0, 0);
    bool valid = (l15 >> 2) == quad;
    float* pl = &P[wave][quad * 16];
#pragma unroll
    for (int r = 0; r < 4; ++r) {
        float v = s[r] * 0.125f;
        float m = fmaxf(v, __shfl_xor(v, 1));
        m = fmaxf(m, __shfl_xor(m, 2));
        float e = exp2f((v - m) * 1.44269504f);
        float sm = e + __shfl_xor(e, 1);
        sm += __shfl_xor(sm, 2);
        if (valid) pl[r * 4 + (l15 & 3)] = e / sm;
    }

    int win = quad, d4 = l15 * 4;
    int w = w0 + win;
    int wi = w >> 5, wj = w & 31;
    const u16b* vb = qkv_lo + ((size_t)(b * 1024 + w) * 4) * 1536 + 1024 + h * 64 + d4;
    float vf[4][4];
#pragma unroll
    for (int tk = 0; tk < 4; ++tk) {
        u16x4 vv = *(const u16x4*)(vb + (size_t)tk * 1536);
#pragma unroll
        for (int j = 0; j < 4; ++j) vf[tk][j] = bf2f(vv[j]);
    }
    int rr[3] = { wi > 0 ? wi - 1 : 0, wi, wi < 31 ? wi + 1 : 31 };
    int cc[3] = { wj > 0 ? wj - 1 : 0, wj, wj < 31 ? wj + 1 : 31 };
    float hv[3][3][4];
    const u16b* hb = out_hi + (size_t)b * 1024 * 512 + h * 64 + d4;
#pragma unroll
    for (int iy = 0; iy < 3; ++iy)
#pragma unroll
        for (int ix = 0; ix < 3; ++ix) {
            u16x4 t = *(const u16x4*)(hb + (size_t)(rr[iy] * 32 + cc[ix]) * 512);
#pragma unroll
            for (int j = 0; j < 4; ++j) hv[iy][ix][j] = bf2f(t[j]);
        }
#pragma unroll
    for (int tq = 0; tq < 4; ++tq) {
        f32x4 pq = *(const f32x4*)&P[wave][win * 16 + tq * 4];
        int py = tq >> 1, px = tq & 1;
        float wy0 = py ? 0.75f : 0.25f, wx0 = px ? 0.75f : 0.25f;
        float wy1 = 1.f - wy0, wx1 = 1.f - wx0;
        u16b ov[4];
#pragma unroll
        for (int j = 0; j < 4; ++j) {
            float o = pq[0] * vf[0][j] + pq[1] * vf[1][j] + pq[2] * vf[2][j] + pq[3] * vf[3][j];
            float vu = wy0 * (wx0 * hv[py][px][j] + wx1 * hv[py][px + 1][j])
                     + wy1 * (wx0 * hv[py + 1][px][j] + wx1 * hv[py + 1][px + 1][j]);
            ov[j] = f2bf(o + vu);
        }
        int n = (wi * 2 + py) * 64 + wj * 2 + px;
        *(u16x4*)(attn_sum + ((size_t)(b * 4096 + n)) * 512 + h * 64 + d4) = *(u16x4*)ov;
    }
}

// ---------------- launch ----------------
extern "C" void kernel_launch(void* const* d_in, const int* in_sizes, int n_in,
                              void* d_out, int out_size, void* d_ws, size_t ws_size,
                              hipStream_t stream) {
    (void)in_sizes; (void)n_in; (void)out_size; (void)ws_size;
    const float* x = (const float*)d_in[0];
    const float* Wqkv = (const float*)d_in[1];
    const float* Wproj = (const float*)d_in[2];
    const float* bproj = (const float*)d_in[3];
    float* out = (float*)d_out;

    char* ws = (char*)d_ws;
    size_t off = 0;
    auto alloc = [&](size_t bytes) { void* p = ws + off; off += bytes; return p; };
    u16b* wqkv_bf = (u16b*)alloc((size_t)1536 * 512 * 2);
    u16b* wproj_bf = (u16b*)alloc((size_t)512 * 512 * 2);
    // xw and x_hi contiguous -> single merged A of 40960 rows; same for qkv_lo|qkv_hi
    u16b* xw      = (u16b*)alloc((size_t)8 * 1024 * 4 * 512 * 2);
    u16b* x_hi    = (u16b*)alloc((size_t)8 * 1024 * 512 * 2);
    u16b* qkv_lo  = (u16b*)alloc((size_t)8 * 4096 * 1536 * 2);
    u16b* qkv_hi  = (u16b*)alloc((size_t)8 * 1024 * 1536 * 2);
    u16b* vt      = (u16b*)alloc((size_t)64 * 64 * 1024 * 2);
    u16b* out_hi  = (u16b*)alloc((size_t)8 * 1024 * 512 * 2);
    u16b* attn_sum= (u16b*)alloc((size_t)8 * 4096 * 512 * 2);

    pool_pack_cast<<<dim3(7168), dim3(256), 0, stream>>>(x, x_hi, xw, Wqkv, Wproj, wqkv_bf, wproj_bf);
    // merged qkv GEMM: M = 32768 (windows) + 8192 (pooled) = 40960 rows
    gemm8<0><<<dim3(960), dim3(512), 0, stream>>>(xw, wqkv_bf, qkv_lo, nullptr, nullptr, 40960, 1536, 512, 6);
    transpose_v<<<dim3(16, 64), dim3(256), 0, stream>>>(qkv_hi, vt);
    attn_hi<<<dim3(64, 16), dim3(256), 0, stream>>>(qkv_hi, vt, out_hi);
    attn_lo_up<<<dim3(4096), dim3(256), 0, stream>>>(qkv_lo, out_hi, attn_sum);
    gemm8<1><<<dim3(256), dim3(512), 0, stream>>>(attn_sum, wproj_bf, nullptr, out, bproj, 32768, 512, 512, 2);
}